// Round 6
// baseline (1258.178 us; speedup 1.0000x reference)
//
#include <hip/hip_runtime.h>
#include <cstdint>

typedef short bf16x8 __attribute__((ext_vector_type(8)));
typedef float f32x4 __attribute__((ext_vector_type(4)));

#define XSTR 392   // xA row stride (bf16 elems): 784B rows -> 2-way LDS banks (free)

__device__ __forceinline__ float bf2f(uint32_t u) {
    union { uint32_t i; float f; } t; t.i = u << 16; return t.f;
}
__device__ __forceinline__ uint16_t f2bf(float f) {
    union { float f; uint32_t i; } t; t.f = f;
    uint32_t x = t.i;
    return (uint16_t)((x + 0x7fffu + ((x >> 16) & 1u)) >> 16);  // RNE
}

// ---------------------------------------------------------------------------
// Fully fused ShiftWindowMSA: one block per (batch, window). No workspace.
// f32 in, f32 out; bf16 only internally (MFMA inputs, q/k/v LDS).
//  phase 1: gather shifted window x (49x384 f32 -> bf16 LDS, row 49 = zeros)
//  phase 2 (x6 head-pairs): QKV GEMM 64x192x384 via 16x16x32 bf16 MFMA.
//          A-frags from LDS; B-frags streamed from global W (L2-hot; each
//          wave owns 3 disjoint n-tiles so W reads are non-redundant).
//  phase 3: per head: S=qk^T+mask (VALU), softmax, PV + LePE, scatter-store.
// ---------------------------------------------------------------------------
__global__ __launch_bounds__(256, 2) void fused_swmsa(
    const float* __restrict__ query,   // (32,3136,384) f32
    const float* __restrict__ qkv_w,   // (1152,384) f32
    const float* __restrict__ qkv_b,   // (1152) f32
    const float* __restrict__ lepe_w,  // (384,1,3,3) f32
    const float* __restrict__ lepe_b,  // (384) f32
    float* __restrict__ out)           // (32,3136,384) f32
{
    __shared__ uint16_t xA[50 * XSTR];   // 39,200 B
    __shared__ uint16_t qs[2][64 * 40];  // 10,240 B (q, pre-scaled)
    __shared__ uint16_t ks_[2][64 * 40]; // 10,240 B
    __shared__ uint16_t vs[2][64 * 32];  //  8,192 B
    __shared__ float    S[49 * 52];      // 10,192 B
    __shared__ float    lw[2][288];      //  2,304 B
    __shared__ float    lb[2][32];       //    256 B
    __shared__ int      ids[49];         //    196 B   => 80,820 B: 2 blocks/CU

    const int tid  = threadIdx.x;
    const int lane = tid & 63;
    const int wave = tid >> 6;
    const int blk  = blockIdx.x;
    const int b    = blk >> 6, wIdx = blk & 63;
    const int wh   = wIdx >> 3, ww = wIdx & 7;
    const float scale = 0.17677669529663687f;  // 32^-0.5

    // ---- phase 1: stage shifted-window x into LDS (bf16), zero pad row ----
    for (int u = tid; u < 50 * 48; u += 256) {
        int row = u / 48, seg = u % 48;
        bf16x8 v8;
        if (row < 49) {
            int i = row / 7, j = row % 7;
            int h = wh * 7 + i + 3; if (h >= 56) h -= 56;   // roll(-3) gather
            int w = ww * 7 + j + 3; if (w >= 56) w -= 56;
            const float* src = query + ((long)b * 3136 + h * 56 + w) * 384 + seg * 8;
            f32x4 x0 = *(const f32x4*)src;
            f32x4 x1 = *(const f32x4*)(src + 4);
            for (int e = 0; e < 4; ++e) {
                v8[e]     = (short)f2bf(x0[e]);
                v8[e + 4] = (short)f2bf(x1[e]);
            }
        } else {
            for (int e = 0; e < 8; ++e) v8[e] = 0;
        }
        *(bf16x8*)(xA + row * XSTR + seg * 8) = v8;
    }
    if (tid < 49) {   // shifted-coord mask region id (matches _attn_mask slices)
        int i = tid / 7, j = tid % 7;
        int rh = (wh < 7) ? 0 : ((i < 4) ? 1 : 2);   // h' <49 | 49..52 | 53..55
        int rw = (ww < 7) ? 0 : ((j < 4) ? 1 : 2);
        ids[tid] = rh * 3 + rw;
    }

    // per-lane MFMA fragment constants
    const int fr = lane & 15, fq = lane >> 4;
    int aoff[4];
    for (int mi = 0; mi < 4; ++mi) {
        int row = mi * 16 + fr; if (row > 49) row = 49;   // pad rows -> zero row
        aoff[mi] = row * XSTR + fq * 8;
    }
    __syncthreads();

    for (int g = 0; g < 6; ++g) {          // head pair (2g, 2g+1)
        // ---- phase 2: GEMM. wave owns n-tiles {3w,3w+1,3w+2} of 12 ----
        f32x4 acc[4][3];
        for (int mi = 0; mi < 4; ++mi)
            for (int c = 0; c < 3; ++c)
                acc[mi][c] = (f32x4){0.f, 0.f, 0.f, 0.f};

        const float* Wp[3]; float bias[3]; int sel[3], c64[3];
        for (int c = 0; c < 3; ++c) {
            int tt = wave * 3 + c;                 // 0..11
            sel[c] = tt >> 2;                      // 0=q 1=k 2=v
            c64[c] = (tt & 3) * 16 + fr;           // col within 64-col pair
            int wrow = sel[c] * 384 + g * 64 + c64[c];
            Wp[c]   = qkv_w + (long)wrow * 384 + fq * 8;
            bias[c] = qkv_b[wrow];
        }

        for (int kk = 0; kk < 384; kk += 32) {
            bf16x8 a[4], bfv[3];
            for (int mi = 0; mi < 4; ++mi)
                a[mi] = *(const bf16x8*)(xA + aoff[mi] + kk);
            for (int c = 0; c < 3; ++c) {
                f32x4 y0 = *(const f32x4*)(Wp[c] + kk);
                f32x4 y1 = *(const f32x4*)(Wp[c] + kk + 4);
                for (int e = 0; e < 4; ++e) {
                    bfv[c][e]     = (short)f2bf(y0[e]);
                    bfv[c][e + 4] = (short)f2bf(y1[e]);
                }
            }
            for (int mi = 0; mi < 4; ++mi)
                for (int c = 0; c < 3; ++c)
                    acc[mi][c] = __builtin_amdgcn_mfma_f32_16x16x32_bf16(
                        a[mi], bfv[c], acc[mi][c], 0, 0, 0);
        }

        __syncthreads();   // (A) prior pair's attention finished reading LDS

        // epilogue: D col=lane&15, row=(lane>>4)*4+r  -> q/k/v LDS (bf16)
        for (int c = 0; c < 3; ++c) {
            int hp = c64[c] >> 5, cc = c64[c] & 31;
            for (int mi = 0; mi < 4; ++mi)
                for (int r = 0; r < 4; ++r) {
                    int row = mi * 16 + fq * 4 + r;
                    float v = acc[mi][c][r] + bias[c];
                    if (sel[c] == 0)      qs[hp][row * 40 + cc] = f2bf(v * scale);
                    else if (sel[c] == 1) ks_[hp][row * 40 + cc] = f2bf(v);
                    else                  vs[hp][row * 32 + cc] = f2bf(v);
                }
        }
        for (int idx = tid; idx < 576; idx += 256)
            lw[idx / 288][idx % 288] = lepe_w[g * 576 + idx];
        if (tid < 64) lb[tid >> 5][tid & 31] = lepe_b[g * 64 + tid];
        __syncthreads();   // (B)

        // ---- phase 3: attention per head ----
        for (int hp = 0; hp < 2; ++hp) {
            int head = g * 2 + hp;

            if (tid < 169) {   // S = q k^T + mask, 13x13 grid of 4x4 tiles
                int tn = tid / 13, tm = tid % 13;
                const uint16_t* qb = qs[hp];
                const uint16_t* kb = ks_[hp];
                float a[4][4] = {};
                for (int k4 = 0; k4 < 8; ++k4) {
                    float qv[4][4], kv[4][4];
                    for (int r = 0; r < 4; ++r) {
                        uint2 u = *(const uint2*)(qb + (tn * 4 + r) * 40 + k4 * 4);
                        qv[r][0] = bf2f(u.x & 0xffff); qv[r][1] = bf2f(u.x >> 16);
                        qv[r][2] = bf2f(u.y & 0xffff); qv[r][3] = bf2f(u.y >> 16);
                    }
                    for (int c = 0; c < 4; ++c) {
                        uint2 u = *(const uint2*)(kb + (tm * 4 + c) * 40 + k4 * 4);
                        kv[c][0] = bf2f(u.x & 0xffff); kv[c][1] = bf2f(u.x >> 16);
                        kv[c][2] = bf2f(u.y & 0xffff); kv[c][3] = bf2f(u.y >> 16);
                    }
                    for (int r = 0; r < 4; ++r)
                        for (int c = 0; c < 4; ++c)
                            for (int e = 0; e < 4; ++e)
                                a[r][c] += qv[r][e] * kv[c][e];
                }
                for (int r = 0; r < 4; ++r)
                    for (int c = 0; c < 4; ++c) {
                        int n = tn * 4 + r, m = tm * 4 + c;
                        if (n < 49)
                            S[n * 52 + m] = (m >= 49) ? -1e30f
                                : a[r][c] + ((ids[n] != ids[m]) ? -100.f : 0.f);
                    }
            }
            __syncthreads();

            if (tid < 49) {   // softmax row
                float mx = -1e30f;
                for (int m = 0; m < 49; ++m) mx = fmaxf(mx, S[tid * 52 + m]);
                float sum = 0.f;
                for (int m = 0; m < 49; ++m) {
                    float e = __expf(S[tid * 52 + m] - mx);
                    S[tid * 52 + m] = e;
                    sum += e;
                }
                float inv = 1.f / sum;
                for (int m = 0; m < 49; ++m) S[tid * 52 + m] *= inv;
            }
            __syncthreads();

            // O = P V + LePE(v), reverse-shift scatter store (f32!)
            for (int idx = tid; idx < 49 * 32; idx += 256) {
                int n = idx >> 5, dd = idx & 31;
                const uint16_t* vb = vs[hp];
                float o = 0.f;
                for (int m = 0; m < 49; ++m)
                    o += S[n * 52 + m] * bf2f(vb[m * 32 + dd]);
                int i = n / 7, j = n % 7;
                float lp = lb[hp][dd];
                for (int ky = 0; ky < 3; ++ky) {
                    int iy = i + ky - 1;
                    if (iy < 0 || iy >= 7) continue;
                    for (int kx = 0; kx < 3; ++kx) {
                        int jx = j + kx - 1;
                        if (jx < 0 || jx >= 7) continue;
                        lp += lw[hp][dd * 9 + ky * 3 + kx] * bf2f(vb[(iy * 7 + jx) * 32 + dd]);
                    }
                }
                int h = wh * 7 + i + 3; if (h >= 56) h -= 56;   // roll(+3) scatter
                int w = ww * 7 + j + 3; if (w >= 56) w -= 56;
                out[((long)b * 3136 + h * 56 + w) * 384 + head * 32 + dd] = o + lp;
            }
            __syncthreads();   // protect S (hp=1) and q/k/v (next pair)
        }
    }
}

// ---------------------------------------------------------------------------
extern "C" void kernel_launch(void* const* d_in, const int* in_sizes, int n_in,
                              void* d_out, int out_size, void* d_ws, size_t ws_size,
                              hipStream_t stream) {
    const float* query  = (const float*)d_in[0];
    const float* qkv_w  = (const float*)d_in[1];
    const float* qkv_b  = (const float*)d_in[2];
    const float* lepe_w = (const float*)d_in[3];
    const float* lepe_b = (const float*)d_in[4];
    float* out = (float*)d_out;
    (void)d_ws; (void)ws_size; (void)in_sizes; (void)n_in; (void)out_size;

    fused_swmsa<<<2048, 256, 0, stream>>>(query, qkv_w, qkv_b, lepe_w, lepe_b, out);
}